// Round 8
// baseline (176.987 us; speedup 1.0000x reference)
//
#include <hip/hip_runtime.h>

#define N  512
#define E  256
#define H  150
#define HP 160
#define JB 64          // j per chunk
#define NCH (N / JB)   // 8

typedef __attribute__((ext_vector_type(8))) short short8;
typedef __attribute__((ext_vector_type(4))) float f32x4;
typedef __attribute__((ext_vector_type(4))) unsigned uint4v;
typedef __attribute__((ext_vector_type(2))) unsigned uint2v;

// Manual RNE f32->bf16 (verified numerics; __float22bfloat162_rn truncates here).
__device__ __forceinline__ unsigned short f2bf(float f) {
    unsigned u = __float_as_uint(f);
    u += 0x7fffu + ((u >> 16) & 1u);          // RNE
    return (unsigned short)(u >> 16);
}
__device__ __forceinline__ unsigned pkbf(float a, float b) {
    return (unsigned)f2bf(a) | ((unsigned)f2bf(b) << 16);
}

// ---------------- kernel 1: A[i,h]=g_i@W1a + b1 (f32), B[j,h]=g_j@W1b (bf16) ----------------
__global__ __launch_bounds__(192) void precompute_ab(
    const float* __restrict__ g, const float* __restrict__ W1,
    const float* __restrict__ b1, float* __restrict__ wsA,
    unsigned short* __restrict__ wsB)
{
    const int i0  = blockIdx.x * 4;
    const int tid = threadIdx.x;
    __shared__ float gi[4][E];
    for (int idx = tid; idx < 4 * E; idx += 192) gi[idx >> 8][idx & 255] = g[i0 * E + idx];
    __syncthreads();
    const int h = tid;
    if (h < HP) {
        float a[4] = {0, 0, 0, 0}, b[4] = {0, 0, 0, 0};
        if (h < H) {
            for (int e = 0; e < E; ++e) {
                const float wa = W1[e * H + h];
                const float wb = W1[(E + e) * H + h];
#pragma unroll
                for (int qq = 0; qq < 4; ++qq) {
                    a[qq] = fmaf(gi[qq][e], wa, a[qq]);
                    b[qq] = fmaf(gi[qq][e], wb, b[qq]);
                }
            }
            const float bb = b1[h];
#pragma unroll
            for (int qq = 0; qq < 4; ++qq) a[qq] += bb;
        }
#pragma unroll
        for (int qq = 0; qq < 4; ++qq) {
            wsA[(i0 + qq) * HP + h] = a[qq];
            wsB[(i0 + qq) * HP + h] = f2bf(b[qq]);
        }
    }
}

// ---------------- kernel 2: fused pairwise MFMA MLP ----------------
// 512 threads = 8 waves = 4 h-quarters x 2 j-halves. Grid 512 = 1 i/block so
// 2 blocks/CU co-reside at VGPR<=128 (R7's grid 256 pinned 1 block/CU).
// h-quarter partition {0-47, 48-95, 96-127, 128-159} — EXACT (R4 overlap bug fixed).
// Chunk loop runs 2 barriers/chunk: P-stage(ch+1) sits after barrier2 (loads
// overlap L2 MFMA), output(ch) deferred past barrier1.
#define OFF_P   0        // P  [64][528B] = 33792
#define OFF_H1  33792    // h1 [64][336B] = 21504 -> 55296
#define OFF_C2  55296    // b2 160 f32 = 640 -> 55936
#define OFF_W3L 55936    // W3 160 f32 = 640 -> 56576
#define OFF_SB  56576    // 4x64 f32 = 1024 -> 57600
#define LDS_SZ  57600
// transients (prologue): W1t [150][272B]=40800, W2t [150][336B]=50400 — both < OFF_C2

__global__ __launch_bounds__(512, 2) void pairwise_mfma(
    const float* __restrict__ g,  const float* __restrict__ ms,
    const float* __restrict__ W1, const float* __restrict__ W2,
    const float* __restrict__ b2, const float* __restrict__ W3,
    const float* __restrict__ b3, const float* __restrict__ wsA,
    const unsigned short* __restrict__ wsB, float* __restrict__ out)
{
    __shared__ __attribute__((aligned(16))) char smem[LDS_SZ];
    float* smf = (float*)smem;
    const int tid  = threadIdx.x;
    const int wave = tid >> 6;
    const int lane = tid & 63;
    const int c    = lane & 15;
    const int q    = lane >> 4;
    const int wq   = wave & 3;      // h-quarter
    const int jh   = wave >> 2;     // j-half (32 j)
    const int hbase  = (wq < 2) ? wq * 48 : 96 + (wq - 2) * 32;
    const int mcount = (wq < 2) ? 3 : 2;
    const short8 z8 = {0, 0, 0, 0, 0, 0, 0, 0};

    // ---- stage W1t (bf16 transposed, stride 272B) in 2 e-passes; 300 threads ----
    short8 w1f[3][8];
    for (int p = 0; p < 2; ++p) {
        if (p) __syncthreads();
        if (tid < 300) {
            const int h = (tid < 150) ? tid : tid - 150;
            const int half = (tid < 150) ? 0 : 1;
            const float* wsrc = W1 + (2 * E + p * 128) * H + h;
            char* dst = smem + h * 272 + half * 128;
#pragma unroll 4
            for (int t = 0; t < 32; ++t) {
                const int ep = half * 32 + t;
                *(unsigned*)(dst + t * 4) = pkbf(wsrc[(2 * ep) * H], wsrc[(2 * ep + 1) * H]);
            }
        }
        __syncthreads();
#pragma unroll
        for (int m = 0; m < 3; ++m) {
            const int hr = hbase + m * 16 + c;
#pragma unroll
            for (int ktp = 0; ktp < 4; ++ktp)
                w1f[m][p * 4 + ktp] = (m < mcount && hr < H)
                    ? *(const short8*)(smem + hr * 272 + (ktp * 32 + q * 8) * 2) : z8;
        }
    }
    __syncthreads();
    // ---- stage W2t (stride 336B); 300 threads; consts in parallel ----
    if (tid < 300) {
        const int h = (tid < 150) ? tid : tid - 150;
        const int half = (tid < 150) ? 0 : 1;
        char* dst = smem + h * 336;
#pragma unroll 4
        for (int t = 0; t < 42; ++t) {
            const int kp = half * 42 + t;
            const float lo = (2 * kp     < H) ? W2[(2 * kp) * H + h]     : 0.0f;
            const float hi = (2 * kp + 1 < H) ? W2[(2 * kp + 1) * H + h] : 0.0f;
            *(unsigned*)(dst + kp * 4) = pkbf(lo, hi);
        }
    }
    if (tid >= 320 && tid < 480) {
        const int hx = tid - 320;
        smf[OFF_C2 / 4 + hx]  = (hx < H) ? b2[hx] : 0.0f;
        smf[OFF_W3L / 4 + hx] = (hx < H) ? W3[hx] : 0.0f;
    }
    __syncthreads();
    short8 w2f[3][5];
#pragma unroll
    for (int m = 0; m < 3; ++m) {
        const int hr = hbase + m * 16 + c;
#pragma unroll
        for (int kt = 0; kt < 5; ++kt)
            w2f[m][kt] = (m < mcount && hr < H)
                ? *(const short8*)(smem + hr * 336 + (kt * 32 + q * 8) * 2) : z8;
    }
    __syncthreads();

    const int jb = tid >> 5;        // 0..15
    const int e0 = (tid & 31) * 8;
    const float b3v = b3[0];
    const int i = blockIdx.x;
    const f32x4 ga = *(const f32x4*)(g + i * E + e0);
    const f32x4 gb = *(const f32x4*)(g + i * E + e0 + 4);
    f32x4 av[3];
#pragma unroll
    for (int m = 0; m < 3; ++m)
        av[m] = (m < mcount) ? *(const f32x4*)(wsA + i * HP + hbase + m * 16 + q * 4)
                             : (f32x4){0, 0, 0, 0};
    const float msi = ms[i];

    // ---- prime: stage P for chunk 0 ----
#pragma unroll
    for (int it = 0; it < 4; ++it) {
        const int jl = jb + it * 16;
        const float* gr = g + jl * E + e0;
        const f32x4 u = *(const f32x4*)gr;
        const f32x4 v = *(const f32x4*)(gr + 4);
        uint4v pk;
        pk[0] = pkbf(u[0] * ga[0], u[1] * ga[1]);
        pk[1] = pkbf(u[2] * ga[2], u[3] * ga[3]);
        pk[2] = pkbf(v[0] * gb[0], v[1] * gb[1]);
        pk[3] = pkbf(v[2] * gb[2], v[3] * gb[3]);
        *(uint4v*)(smem + OFF_P + jl * 528 + e0 * 2) = pk;
    }
    __syncthreads();

    for (int ch = 0; ch < NCH; ++ch) {
        const int j0 = ch * JB;

        // ---- layer 1: D[h][j] = mfma(w1f, P-frag) ----
        f32x4 acc[2][3];
#pragma unroll
        for (int jt = 0; jt < 2; ++jt)
#pragma unroll
            for (int m = 0; m < 3; ++m) acc[jt][m] = (f32x4){0, 0, 0, 0};
#pragma unroll
        for (int kt = 0; kt < 8; ++kt) {
            short8 pf[2];
#pragma unroll
            for (int jt = 0; jt < 2; ++jt)
                pf[jt] = *(const short8*)(smem + OFF_P + (jh * 32 + jt * 16 + c) * 528 + (kt * 32 + q * 8) * 2);
#pragma unroll
            for (int m = 0; m < 3; ++m)
                if (m < mcount)
#pragma unroll
                    for (int jt = 0; jt < 2; ++jt)
                        acc[jt][m] = __builtin_amdgcn_mfma_f32_16x16x32_bf16(w1f[m][kt], pf[jt], acc[jt][m], 0, 0, 0);
        }
        // ---- epi 1: h1[j][h] = relu(acc + A_i[h] + B[j][h]) ----
#pragma unroll
        for (int m = 0; m < 3; ++m)
            if (m < mcount) {
                const int h0 = hbase + m * 16 + q * 4;
#pragma unroll
                for (int jt = 0; jt < 2; ++jt) {
                    const int j = jh * 32 + jt * 16 + c;
                    const uint2v bv = *(const uint2v*)(wsB + (j0 + j) * HP + h0);
                    const float v0 = fmaxf(acc[jt][m][0] + av[m][0] + __uint_as_float(bv[0] << 16), 0.0f);
                    const float v1 = fmaxf(acc[jt][m][1] + av[m][1] + __uint_as_float(bv[0] & 0xffff0000u), 0.0f);
                    const float v2 = fmaxf(acc[jt][m][2] + av[m][2] + __uint_as_float(bv[1] << 16), 0.0f);
                    const float v3 = fmaxf(acc[jt][m][3] + av[m][3] + __uint_as_float(bv[1] & 0xffff0000u), 0.0f);
                    uint2v hw;
                    hw[0] = pkbf(v0, v1);
                    hw[1] = pkbf(v2, v3);
                    *(uint2v*)(smem + OFF_H1 + j * 336 + h0 * 2) = hw;
                }
            }
        __syncthreads();   // barrier2: h1 ready; P(ch) reads done

        // ---- layer 2: reuse acc ----
#pragma unroll
        for (int jt = 0; jt < 2; ++jt)
#pragma unroll
            for (int m = 0; m < 3; ++m) acc[jt][m] = (f32x4){0, 0, 0, 0};
#pragma unroll
        for (int kt = 0; kt < 5; ++kt) {
            short8 hf[2];
#pragma unroll
            for (int jt = 0; jt < 2; ++jt)
                hf[jt] = *(const short8*)(smem + OFF_H1 + (jh * 32 + jt * 16 + c) * 336 + (kt * 32 + q * 8) * 2);
#pragma unroll
            for (int m = 0; m < 3; ++m)
                if (m < mcount)
#pragma unroll
                    for (int jt = 0; jt < 2; ++jt)
                        acc[jt][m] = __builtin_amdgcn_mfma_f32_16x16x32_bf16(w2f[m][kt], hf[jt], acc[jt][m], 0, 0, 0);
        }
        // ---- epi 2 + layer 3: partials -> SB ----
        float part[2] = {0.0f, 0.0f};
#pragma unroll
        for (int m = 0; m < 3; ++m)
            if (m < mcount) {
                const int h0 = hbase + m * 16 + q * 4;
                const f32x4 b2v = *(const f32x4*)(smf + OFF_C2 / 4 + h0);
                const f32x4 w3v = *(const f32x4*)(smf + OFF_W3L / 4 + h0);
#pragma unroll
                for (int jt = 0; jt < 2; ++jt)
#pragma unroll
                    for (int r = 0; r < 4; ++r)
                        part[jt] = fmaf(fmaxf(acc[jt][m][r] + b2v[r], 0.0f), w3v[r], part[jt]);
            }
#pragma unroll
        for (int jt = 0; jt < 2; ++jt) {
            float pv = part[jt];
            pv += __shfl_xor(pv, 16);
            pv += __shfl_xor(pv, 32);
            if (q == 0) smf[OFF_SB / 4 + wq * 64 + jh * 32 + jt * 16 + c] = pv;
        }
        // ---- stage P for ch+1 (loads overlap L2 mfma above; P(ch) reads done at barrier2) ----
        if (ch + 1 < NCH) {
            const int jn = (ch + 1) * JB;
#pragma unroll
            for (int it = 0; it < 4; ++it) {
                const int jl = jb + it * 16;
                const float* gr = g + (jn + jl) * E + e0;
                const f32x4 u = *(const f32x4*)gr;
                const f32x4 v = *(const f32x4*)(gr + 4);
                uint4v pk;
                pk[0] = pkbf(u[0] * ga[0], u[1] * ga[1]);
                pk[1] = pkbf(u[2] * ga[2], u[3] * ga[3]);
                pk[2] = pkbf(v[0] * gb[0], v[1] * gb[1]);
                pk[3] = pkbf(v[2] * gb[2], v[3] * gb[3]);
                *(uint4v*)(smem + OFF_P + jl * 528 + e0 * 2) = pk;
            }
        }
        __syncthreads();   // barrier1: SB + P(ch+1) ready

        // ---- output chunk ch ----
        if (tid < JB) {
            const int j = j0 + tid;
            const float s = smf[OFF_SB / 4 + tid] + smf[OFF_SB / 4 + 64 + tid]
                          + smf[OFF_SB / 4 + 128 + tid] + smf[OFF_SB / 4 + 192 + tid] + b3v;
            out[i * N + j] = (msi + ms[j] + s) * (1.0f / 3.0f);
        }
    }
}

extern "C" void kernel_launch(void* const* d_in, const int* in_sizes, int n_in,
                              void* d_out, int out_size, void* d_ws, size_t ws_size,
                              hipStream_t stream) {
    const float* g  = (const float*)d_in[0];
    const float* ms = (const float*)d_in[1];
    const float* W1 = (const float*)d_in[2];
    const float* b1 = (const float*)d_in[3];
    const float* W2 = (const float*)d_in[4];
    const float* b2 = (const float*)d_in[5];
    const float* W3 = (const float*)d_in[6];
    const float* b3 = (const float*)d_in[7];
    float* out = (float*)d_out;
    float* wsA = (float*)d_ws;                                         // 512*160 f32
    unsigned short* wsB = (unsigned short*)((char*)d_ws + N * HP * 4); // 512*160 bf16

    precompute_ab<<<N / 4, 192, 0, stream>>>(g, W1, b1, wsA, wsB);
    pairwise_mfma<<<N, 512, 0, stream>>>(g, ms, W1, W2, b2, W3, b3, wsA, wsB, out);
}

// Round 10
// 171.810 us; speedup vs baseline: 1.0301x; 1.0301x over previous
//
#include <hip/hip_runtime.h>

#define N  512
#define E  256
#define H  150
#define HP 160
#define JB 64          // j per chunk
#define NCH (N / JB)   // 8

typedef __attribute__((ext_vector_type(8))) short short8;
typedef __attribute__((ext_vector_type(4))) float f32x4;
typedef __attribute__((ext_vector_type(4))) unsigned uint4v;
typedef __attribute__((ext_vector_type(2))) unsigned uint2v;

// Manual RNE f32->bf16 (verified numerics; __float22bfloat162_rn truncates here).
__device__ __forceinline__ unsigned short f2bf(float f) {
    unsigned u = __float_as_uint(f);
    u += 0x7fffu + ((u >> 16) & 1u);          // RNE
    return (unsigned short)(u >> 16);
}
__device__ __forceinline__ unsigned pkbf(float a, float b) {
    return (unsigned)f2bf(a) | ((unsigned)f2bf(b) << 16);
}

// ---------------- kernel 1: A[i,h]=g_i@W1a + b1 (f32), B[j,h]=g_j@W1b (bf16) ----------------
__global__ __launch_bounds__(192) void precompute_ab(
    const float* __restrict__ g, const float* __restrict__ W1,
    const float* __restrict__ b1, float* __restrict__ wsA,
    unsigned short* __restrict__ wsB)
{
    const int i0  = blockIdx.x * 4;
    const int tid = threadIdx.x;
    __shared__ float gi[4][E];
    for (int idx = tid; idx < 4 * E; idx += 192) gi[idx >> 8][idx & 255] = g[i0 * E + idx];
    __syncthreads();
    const int h = tid;
    if (h < HP) {
        float a[4] = {0, 0, 0, 0}, b[4] = {0, 0, 0, 0};
        if (h < H) {
            for (int e = 0; e < E; ++e) {
                const float wa = W1[e * H + h];
                const float wb = W1[(E + e) * H + h];
#pragma unroll
                for (int qq = 0; qq < 4; ++qq) {
                    a[qq] = fmaf(gi[qq][e], wa, a[qq]);
                    b[qq] = fmaf(gi[qq][e], wb, b[qq]);
                }
            }
            const float bb = b1[h];
#pragma unroll
            for (int qq = 0; qq < 4; ++qq) a[qq] += bb;
        }
#pragma unroll
        for (int qq = 0; qq < 4; ++qq) {
            wsA[(i0 + qq) * HP + h] = a[qq];
            wsB[(i0 + qq) * HP + h] = f2bf(b[qq]);
        }
    }
}

// ---------------- kernel 2: fused pairwise MFMA MLP ----------------
// 512 threads = 8 waves = 4 h-quarters x 2 j-halves (jt=2). ONLY this 8-wave
// shape is numerics-verified (R3/R6/R7/R8 pass; 4-wave jt=4 variants R4/R5/R9
// all fail ~0.09 with layout-dependent garbage — shape banned).
// Grid 256, 2 i's per block: one prologue per CU (R8's grid-512 ran it twice).
// 2 barriers per chunk (R8's verified body): P-stage(ch+1) after the L2 MFMA,
// output(ch) deferred past the second barrier.
// Staging writes are b128 (uniform bank coverage: any 16B-aligned stride is
// ≡0 mod 4 dw -> gcd>=4 -> lockstep DWORD row-staging is >=8-way conflicted
// no matter the stride; 16B writes hit all 32 banks uniformly).
#define OFF_P   0        // P  [64][528B] = 33792
#define OFF_H1  33792    // h1 [64][336B] = 21504 -> 55296
#define OFF_C2  55296    // b2 160 f32 = 640 -> 55936
#define OFF_W3L 55936    // W3 160 f32 = 640 -> 56576
#define OFF_SB  56576    // 4x64 f32 = 1024 -> 57600
#define LDS_SZ  57600
// transients (prologue): W1t [150][272B]=40800, W2t [150][336B]=50400 — both < OFF_C2

__global__ __launch_bounds__(512, 2) void pairwise_mfma(
    const float* __restrict__ g,  const float* __restrict__ ms,
    const float* __restrict__ W1, const float* __restrict__ W2,
    const float* __restrict__ b2, const float* __restrict__ W3,
    const float* __restrict__ b3, const float* __restrict__ wsA,
    const unsigned short* __restrict__ wsB, float* __restrict__ out)
{
    __shared__ __attribute__((aligned(16))) char smem[LDS_SZ];
    float* smf = (float*)smem;
    const int tid  = threadIdx.x;
    const int wave = tid >> 6;
    const int lane = tid & 63;
    const int c    = lane & 15;
    const int q    = lane >> 4;
    const int wq   = wave & 3;      // h-quarter
    const int jh   = wave >> 2;     // j-half (32 j)
    const int hbase  = (wq < 2) ? wq * 48 : 96 + (wq - 2) * 32;
    const int mcount = (wq < 2) ? 3 : 2;
    const short8 z8 = {0, 0, 0, 0, 0, 0, 0, 0};

    // ---- stage W1t (bf16 transposed, stride 272B) in 2 e-passes; b128 writes ----
    short8 w1f[3][8];
    for (int p = 0; p < 2; ++p) {
        if (p) __syncthreads();
        if (tid < 300) {
            const int h    = (tid < 150) ? tid : tid - 150;
            const int half = (tid < 150) ? 0 : 1;
            const float* wsrc = W1 + (2 * E + p * 128) * H + h;
            char* dst = smem + h * 272 + half * 128;
#pragma unroll
            for (int t = 0; t < 8; ++t) {
                const int e8 = (half * 8 + t) * 8;
                uint4v pk;
                pk[0] = pkbf(wsrc[(e8 + 0) * H], wsrc[(e8 + 1) * H]);
                pk[1] = pkbf(wsrc[(e8 + 2) * H], wsrc[(e8 + 3) * H]);
                pk[2] = pkbf(wsrc[(e8 + 4) * H], wsrc[(e8 + 5) * H]);
                pk[3] = pkbf(wsrc[(e8 + 6) * H], wsrc[(e8 + 7) * H]);
                *(uint4v*)(dst + t * 16) = pk;
            }
        }
        __syncthreads();
#pragma unroll
        for (int m = 0; m < 3; ++m) {
            const int hr = hbase + m * 16 + c;
#pragma unroll
            for (int ktp = 0; ktp < 4; ++ktp)
                w1f[m][p * 4 + ktp] = (m < mcount && hr < H)
                    ? *(const short8*)(smem + hr * 272 + (ktp * 32 + q * 8) * 2) : z8;
        }
    }
    __syncthreads();
    // ---- stage W2t (stride 336B = 21 x 16B blocks); b128 writes; consts in parallel ----
    if (tid < 300) {
        const int h  = (tid < 150) ? tid : tid - 150;
        const int lo = (tid < 150) ? 0 : 11;
        const int hi = (tid < 150) ? 11 : 21;
        char* dst = smem + h * 336;
        for (int t = lo; t < hi; ++t) {
            const int k8 = t * 8;
            uint4v pk;
#pragma unroll
            for (int x = 0; x < 4; ++x) {
                const int ka = k8 + 2 * x, kb = k8 + 2 * x + 1;
                const float va = (ka < H) ? W2[ka * H + h] : 0.0f;
                const float vb = (kb < H) ? W2[kb * H + h] : 0.0f;
                pk[x] = pkbf(va, vb);
            }
            *(uint4v*)(dst + t * 16) = pk;
        }
    }
    if (tid >= 320 && tid < 480) {
        const int hx = tid - 320;
        smf[OFF_C2 / 4 + hx]  = (hx < H) ? b2[hx] : 0.0f;
        smf[OFF_W3L / 4 + hx] = (hx < H) ? W3[hx] : 0.0f;
    }
    __syncthreads();
    short8 w2f[3][5];
#pragma unroll
    for (int m = 0; m < 3; ++m) {
        const int hr = hbase + m * 16 + c;
#pragma unroll
        for (int kt = 0; kt < 5; ++kt)
            w2f[m][kt] = (m < mcount && hr < H)
                ? *(const short8*)(smem + hr * 336 + (kt * 32 + q * 8) * 2) : z8;
    }
    __syncthreads();

    const int jb = tid >> 5;        // 0..15
    const int e0 = (tid & 31) * 8;
    const float b3v = b3[0];

    for (int ii = 0; ii < 2; ++ii) {
        const int i = blockIdx.x * 2 + ii;
        const f32x4 ga = *(const f32x4*)(g + i * E + e0);
        const f32x4 gb = *(const f32x4*)(g + i * E + e0 + 4);
        f32x4 av[3];
#pragma unroll
        for (int m = 0; m < 3; ++m)
            av[m] = (m < mcount) ? *(const f32x4*)(wsA + i * HP + hbase + m * 16 + q * 4)
                                 : (f32x4){0, 0, 0, 0};
        const float msi = ms[i];

        // ---- prime: stage P for chunk 0 ----
#pragma unroll
        for (int it = 0; it < 4; ++it) {
            const int jl = jb + it * 16;
            const float* gr = g + jl * E + e0;
            const f32x4 u = *(const f32x4*)gr;
            const f32x4 v = *(const f32x4*)(gr + 4);
            uint4v pk;
            pk[0] = pkbf(u[0] * ga[0], u[1] * ga[1]);
            pk[1] = pkbf(u[2] * ga[2], u[3] * ga[3]);
            pk[2] = pkbf(v[0] * gb[0], v[1] * gb[1]);
            pk[3] = pkbf(v[2] * gb[2], v[3] * gb[3]);
            *(uint4v*)(smem + OFF_P + jl * 528 + e0 * 2) = pk;
        }
        __syncthreads();

        for (int ch = 0; ch < NCH; ++ch) {
            const int j0 = ch * JB;

            // ---- layer 1: D[h][j] = mfma(w1f, P-frag) ----
            f32x4 acc[2][3];
#pragma unroll
            for (int jt = 0; jt < 2; ++jt)
#pragma unroll
                for (int m = 0; m < 3; ++m) acc[jt][m] = (f32x4){0, 0, 0, 0};
#pragma unroll
            for (int kt = 0; kt < 8; ++kt) {
                short8 pf[2];
#pragma unroll
                for (int jt = 0; jt < 2; ++jt)
                    pf[jt] = *(const short8*)(smem + OFF_P + (jh * 32 + jt * 16 + c) * 528 + (kt * 32 + q * 8) * 2);
#pragma unroll
                for (int m = 0; m < 3; ++m)
                    if (m < mcount)
#pragma unroll
                        for (int jt = 0; jt < 2; ++jt)
                            acc[jt][m] = __builtin_amdgcn_mfma_f32_16x16x32_bf16(w1f[m][kt], pf[jt], acc[jt][m], 0, 0, 0);
            }
            // ---- epi 1: h1[j][h] = relu(acc + A_i[h] + B[j][h]) ----
#pragma unroll
            for (int m = 0; m < 3; ++m)
                if (m < mcount) {
                    const int h0 = hbase + m * 16 + q * 4;
#pragma unroll
                    for (int jt = 0; jt < 2; ++jt) {
                        const int j = jh * 32 + jt * 16 + c;
                        const uint2v bv = *(const uint2v*)(wsB + (j0 + j) * HP + h0);
                        const float v0 = fmaxf(acc[jt][m][0] + av[m][0] + __uint_as_float(bv[0] << 16), 0.0f);
                        const float v1 = fmaxf(acc[jt][m][1] + av[m][1] + __uint_as_float(bv[0] & 0xffff0000u), 0.0f);
                        const float v2 = fmaxf(acc[jt][m][2] + av[m][2] + __uint_as_float(bv[1] << 16), 0.0f);
                        const float v3 = fmaxf(acc[jt][m][3] + av[m][3] + __uint_as_float(bv[1] & 0xffff0000u), 0.0f);
                        uint2v hw;
                        hw[0] = pkbf(v0, v1);
                        hw[1] = pkbf(v2, v3);
                        *(uint2v*)(smem + OFF_H1 + j * 336 + h0 * 2) = hw;
                    }
                }
            __syncthreads();   // barrier2: h1 ready; P(ch) reads done

            // ---- layer 2: reuse acc ----
#pragma unroll
            for (int jt = 0; jt < 2; ++jt)
#pragma unroll
                for (int m = 0; m < 3; ++m) acc[jt][m] = (f32x4){0, 0, 0, 0};
#pragma unroll
            for (int kt = 0; kt < 5; ++kt) {
                short8 hf[2];
#pragma unroll
                for (int jt = 0; jt < 2; ++jt)
                    hf[jt] = *(const short8*)(smem + OFF_H1 + (jh * 32 + jt * 16 + c) * 336 + (kt * 32 + q * 8) * 2);
#pragma unroll
                for (int m = 0; m < 3; ++m)
                    if (m < mcount)
#pragma unroll
                        for (int jt = 0; jt < 2; ++jt)
                            acc[jt][m] = __builtin_amdgcn_mfma_f32_16x16x32_bf16(w2f[m][kt], hf[jt], acc[jt][m], 0, 0, 0);
            }
            // ---- epi 2 + layer 3: partials -> SB ----
            float part[2] = {0.0f, 0.0f};
#pragma unroll
            for (int m = 0; m < 3; ++m)
                if (m < mcount) {
                    const int h0 = hbase + m * 16 + q * 4;
                    const f32x4 b2v = *(const f32x4*)(smf + OFF_C2 / 4 + h0);
                    const f32x4 w3v = *(const f32x4*)(smf + OFF_W3L / 4 + h0);
#pragma unroll
                    for (int jt = 0; jt < 2; ++jt)
#pragma unroll
                        for (int r = 0; r < 4; ++r)
                            part[jt] = fmaf(fmaxf(acc[jt][m][r] + b2v[r], 0.0f), w3v[r], part[jt]);
                }
#pragma unroll
            for (int jt = 0; jt < 2; ++jt) {
                float pv = part[jt];
                pv += __shfl_xor(pv, 16);
                pv += __shfl_xor(pv, 32);
                if (q == 0) smf[OFF_SB / 4 + wq * 64 + jh * 32 + jt * 16 + c] = pv;
            }
            // ---- stage P for ch+1 (global loads overlap epi; P(ch) reads done at barrier2) ----
            if (ch + 1 < NCH) {
                const int jn = (ch + 1) * JB;
#pragma unroll
                for (int it = 0; it < 4; ++it) {
                    const int jl = jb + it * 16;
                    const float* gr = g + (jn + jl) * E + e0;
                    const f32x4 u = *(const f32x4*)gr;
                    const f32x4 v = *(const f32x4*)(gr + 4);
                    uint4v pk;
                    pk[0] = pkbf(u[0] * ga[0], u[1] * ga[1]);
                    pk[1] = pkbf(u[2] * ga[2], u[3] * ga[3]);
                    pk[2] = pkbf(v[0] * gb[0], v[1] * gb[1]);
                    pk[3] = pkbf(v[2] * gb[2], v[3] * gb[3]);
                    *(uint4v*)(smem + OFF_P + jl * 528 + e0 * 2) = pk;
                }
            }
            __syncthreads();   // barrier1: SB + P(ch+1) ready

            // ---- output chunk ch ----
            if (tid < JB) {
                const int j = j0 + tid;
                const float s = smf[OFF_SB / 4 + tid] + smf[OFF_SB / 4 + 64 + tid]
                              + smf[OFF_SB / 4 + 128 + tid] + smf[OFF_SB / 4 + 192 + tid] + b3v;
                out[i * N + j] = (msi + ms[j] + s) * (1.0f / 3.0f);
            }
        }
    }
}

extern "C" void kernel_launch(void* const* d_in, const int* in_sizes, int n_in,
                              void* d_out, int out_size, void* d_ws, size_t ws_size,
                              hipStream_t stream) {
    const float* g  = (const float*)d_in[0];
    const float* ms = (const float*)d_in[1];
    const float* W1 = (const float*)d_in[2];
    const float* b1 = (const float*)d_in[3];
    const float* W2 = (const float*)d_in[4];
    const float* b2 = (const float*)d_in[5];
    const float* W3 = (const float*)d_in[6];
    const float* b3 = (const float*)d_in[7];
    float* out = (float*)d_out;
    float* wsA = (float*)d_ws;                                         // 512*160 f32
    unsigned short* wsB = (unsigned short*)((char*)d_ws + N * HP * 4); // 512*160 bf16

    precompute_ab<<<N / 4, 192, 0, stream>>>(g, W1, b1, wsA, wsB);
    pairwise_mfma<<<N / 2, 512, 0, stream>>>(g, ms, W1, W2, b2, W3, b3, wsA, wsB, out);
}